// Round 1
// baseline (296.091 us; speedup 1.0000x reference)
//
#include <hip/hip_runtime.h>
#include <hip/hip_bf16.h>

// GlobalFilter: y = irfft2(rfft2(x, ortho) * W, ortho)  ==  per-channel 14x14
// circular convolution with kernel R_c = (1/196) * Re(IFFT2(Wext_c)).
//
// x: (256, 196, 512) fp32, W: (14, 8, 512, 2) fp32, out: (256, 196, 512) fp32.
// d_ws holds R: (196, 512) fp32 = 401,408 B (recomputed every launch since ws
// is re-poisoned).

#define Hs 14
#define Ns 196          // 14*14
#define Cc 512
#define CT 32           // channel tile
#define CONV_THREADS (CT * Hs)   // 448 = 32 c-lanes x 14 m-rows

// ---------------------------------------------------------------------------
// Prep: R[s=dm*14+dn][c] = (1/196) * sum_{h,w in 0..13} Re(Wext[h,w,c] * e^{i*2pi*(h*dm+w*dn)/14})
// Wext[h,w,c] = W[h,w,c]                      for w <= 7
//             = conj(W[(14-h)%14, 14-w, c])   for w >= 8
// ---------------------------------------------------------------------------
__global__ __launch_bounds__(256) void prep_kernel(const float* __restrict__ cw,
                                                   float* __restrict__ R) {
    __shared__ float cs[14], sn[14];
    if (threadIdx.x < 14) {
        float ang = (float)threadIdx.x * 0.44879895051282760549f;  // 2*pi/14
        cs[threadIdx.x] = cosf(ang);
        sn[threadIdx.x] = sinf(ang);
    }
    __syncthreads();

    int gid = blockIdx.x * 256 + threadIdx.x;   // 196*512 = 100352 = 392*256
    int c = gid & 511;
    int s = gid >> 9;          // 0..195
    int dm = s / 14;
    int dn = s % 14;

    float acc = 0.0f;
    int kh = 0;                              // (h*dm) % 14, incremental
    for (int h = 0; h < 14; ++h) {
        int h2 = (h == 0) ? 0 : (14 - h);
        int k = kh;                          // (h*dm + w*dn) % 14
        #pragma unroll
        for (int w = 0; w < 14; ++w) {
            float Ar, Ai;
            if (w <= 7) {
                const float* p = cw + (size_t)(((h * 8 + w) * 512 + c) * 2);
                Ar = p[0]; Ai = p[1];
            } else {
                const float* p = cw + (size_t)(((h2 * 8 + (14 - w)) * 512 + c) * 2);
                Ar = p[0]; Ai = -p[1];
            }
            acc += Ar * cs[k] - Ai * sn[k];
            k += dn; if (k >= 14) k -= 14;
        }
        kh += dm; if (kh >= 14) kh -= 14;
    }
    R[s * 512 + c] = acc * (1.0f / 196.0f);
}

// ---------------------------------------------------------------------------
// Main: per-channel circular conv.
// Block = one batch b x one 32-channel tile. 448 threads = (c 0..31) x (m 0..13).
// Each thread computes y[b, m, 0..13, c]: acc[14] in registers.
// 7 FMAs per LDS read (x value reused over 14 n's; R row reused over 14 q's).
// ---------------------------------------------------------------------------
__global__ __launch_bounds__(CONV_THREADS) void conv_kernel(
        const float* __restrict__ x,
        const float* __restrict__ R,
        float* __restrict__ out) {
    __shared__ float xs[Ns * CT];   // 25,088 B
    __shared__ float rs[Ns * CT];   // 25,088 B

    const int bx = blockIdx.x;
    const int ct = bx & 15;          // 16 channel tiles of 32
    const int b  = bx >> 4;
    const int c0 = ct * CT;
    const int t  = threadIdx.x;

    const float* xb = x + (size_t)b * Ns * Cc + c0;
    const float* Rb = R + c0;
    // cooperative load: 196*32 = 6272 elems each, 448 threads -> 14 iters
    for (int i = t; i < Ns * CT; i += CONV_THREADS) {
        int pq = i >> 5;          // / CT
        int cc = i & (CT - 1);
        xs[pq * CT + cc] = xb[pq * Cc + cc];
        rs[pq * CT + cc] = Rb[pq * Cc + cc];
    }
    __syncthreads();

    const int c = t & (CT - 1);
    const int m = t >> 5;             // 0..13 (wave-half-uniform)

    float acc[14];
    #pragma unroll
    for (int n = 0; n < 14; ++n) acc[n] = 0.0f;

    #pragma unroll 1
    for (int p = 0; p < 14; ++p) {
        int dm = m - p; if (dm < 0) dm += 14;
        float Rr[14];
        #pragma unroll
        for (int dn = 0; dn < 14; ++dn) Rr[dn] = rs[(dm * 14 + dn) * CT + c];
        #pragma unroll
        for (int q = 0; q < 14; ++q) {
            float xv = xs[(p * 14 + q) * CT + c];
            #pragma unroll
            for (int n = 0; n < 14; ++n) {
                acc[n] += xv * Rr[(n - q + 14) % 14];   // compile-time index
            }
        }
    }

    float* ob = out + (size_t)b * Ns * Cc + (size_t)(m * 14) * Cc + c0 + c;
    #pragma unroll
    for (int n = 0; n < 14; ++n) ob[n * Cc] = acc[n];
}

extern "C" void kernel_launch(void* const* d_in, const int* in_sizes, int n_in,
                              void* d_out, int out_size, void* d_ws, size_t ws_size,
                              hipStream_t stream) {
    const float* x  = (const float*)d_in[0];
    const float* cw = (const float*)d_in[1];
    float* outp = (float*)d_out;
    float* R = (float*)d_ws;    // 196*512 floats = 401,408 B

    prep_kernel<<<392, 256, 0, stream>>>(cw, R);
    conv_kernel<<<256 * 16, CONV_THREADS, 0, stream>>>(x, R, outp);
}

// Round 2
// 270.453 us; speedup vs baseline: 1.0948x; 1.0948x over previous
//
#include <hip/hip_runtime.h>
#include <hip/hip_bf16.h>

// GlobalFilter: y = irfft2(rfft2(x, ortho) * W, ortho)  ==  per-channel 14x14
// circular convolution with kernel R_c = (1/196) * Re(IFFT2(Wext_c)).
//
// x: (256, 196, 512) fp32, W: (14, 8, 512, 2) fp32, out: (256, 196, 512) fp32.
//
// ws layout: R  at offset 0            : 196*512 floats  (401,408 B)
//            T  at offset 196*512      : 14*14*512*2 floats (802,816 B)  [complex]
// (recomputed every launch; ws is re-poisoned by the harness)

#define Hs 14
#define Ns 196          // 14*14
#define Cc 512
#define CT 32           // channel tile
#define CONV_THREADS 448  // 2 batches x 32 c x 7 m-pairs

typedef float v2f __attribute__((ext_vector_type(2)));

// ---------------------------------------------------------------------------
// Prep stage A:  T[h][dn][c] = sum_{w=0..7} W[h,w,c]   * z^{+w*dn}
//                            + sum_{w=1..6} conj(W[h2,w,c]) * z^{-w*dn}
// with z = e^{i*2pi/14}, h2 = (14-h)%14.  (This is sum_w Wext[h,w,c] z^{w*dn}.)
// ---------------------------------------------------------------------------
__global__ __launch_bounds__(256) void prep_a_kernel(const float* __restrict__ cw,
                                                     float* __restrict__ T) {
    __shared__ float cs[14], sn[14];
    if (threadIdx.x < 14) {
        float ang = (float)threadIdx.x * 0.44879895051282760549f;  // 2*pi/14
        cs[threadIdx.x] = cosf(ang);
        sn[threadIdx.x] = sinf(ang);
    }
    __syncthreads();

    int gid = blockIdx.x * 256 + threadIdx.x;   // 14*14*512 = 100352 = 392*256
    int c = gid & 511;
    int s = gid >> 9;          // h*14 + dn
    int h = s / 14;
    int dn = s % 14;
    int h2 = (h == 0) ? 0 : (14 - h);

    float Tr = 0.0f, Ti = 0.0f;
    // w = 0..7 (direct terms), angle +w*dn
    int k = 0;
    #pragma unroll
    for (int w = 0; w < 8; ++w) {
        const float* p = cw + (size_t)(((h * 8 + w) * 512 + c) * 2);
        float Wr = p[0], Wi = p[1];
        Tr += Wr * cs[k] - Wi * sn[k];
        Ti += Wr * sn[k] + Wi * cs[k];
        k += dn; if (k >= 14) k -= 14;
    }
    // w = 1..6 (mirror terms): conj(W[h2,w,c]) * (cs[k] - i*sn[k])
    int k2 = dn; if (k2 >= 14) k2 -= 14;
    #pragma unroll
    for (int w = 1; w < 7; ++w) {
        const float* p = cw + (size_t)(((h2 * 8 + w) * 512 + c) * 2);
        float Wr = p[0], Wi = p[1];
        Tr += Wr * cs[k2] - Wi * sn[k2];
        Ti -= Wr * sn[k2] + Wi * cs[k2];
        k2 += dn; if (k2 >= 14) k2 -= 14;
    }
    float* o = T + (size_t)(s * 512 + c) * 2;
    o[0] = Tr;
    o[1] = Ti;
}

// ---------------------------------------------------------------------------
// Prep stage B:  R[dm*14+dn][c] = (1/196) * sum_h (Tr[h,dn,c]*cs[(h*dm)%14]
//                                                - Ti[h,dn,c]*sn[(h*dm)%14])
// ---------------------------------------------------------------------------
__global__ __launch_bounds__(256) void prep_b_kernel(const float* __restrict__ T,
                                                     float* __restrict__ R) {
    __shared__ float cs[14], sn[14];
    if (threadIdx.x < 14) {
        float ang = (float)threadIdx.x * 0.44879895051282760549f;  // 2*pi/14
        cs[threadIdx.x] = cosf(ang);
        sn[threadIdx.x] = sinf(ang);
    }
    __syncthreads();

    int gid = blockIdx.x * 256 + threadIdx.x;   // 196*512
    int c = gid & 511;
    int s = gid >> 9;          // dm*14 + dn
    int dm = s / 14;
    int dn = s % 14;

    float acc = 0.0f;
    int kh = 0;
    #pragma unroll
    for (int h = 0; h < 14; ++h) {
        const float* p = T + (size_t)(((h * 14 + dn) * 512 + c) * 2);
        acc += p[0] * cs[kh] - p[1] * sn[kh];
        kh += dm; if (kh >= 14) kh -= 14;
    }
    R[s * 512 + c] = acc * (1.0f / 196.0f);
}

// ---------------------------------------------------------------------------
// Main conv: block = 2 batches x 32-channel tile. 448 threads:
//   c = tid&31, r = tid>>5 (0..13): bsel = r>=7, m = r - 7*bsel.
// Each thread computes rows m and m+7 (all 14 n) for its (b, c) as packed
// float2 (v_pk_fma_f32): acc[n] = (y[m,n], y[m+7,n]).
// ---------------------------------------------------------------------------
__global__ __launch_bounds__(CONV_THREADS, 3) void conv_kernel(
        const float* __restrict__ x,
        const float* __restrict__ R,
        float* __restrict__ out) {
    __shared__ float xs[2 * Ns * CT];   // 50,176 B (two batches)
    __shared__ float rs[Ns * CT];       // 25,088 B

    const int bx = blockIdx.x;          // 2048 blocks
    const int ct = bx & 15;             // 16 channel tiles of 32
    const int bp = bx >> 4;             // 0..127 batch pairs
    const int c0 = ct * CT;
    const int b0 = bp * 2;
    const int t  = threadIdx.x;

    const float* xb = x + (size_t)b0 * Ns * Cc + c0;
    const float* Rb = R + c0;
    // cooperative load: 6272 elems per array slice, 448 threads -> 14 iters
    for (int i = t; i < Ns * CT; i += CONV_THREADS) {
        int pq = i >> 5;
        int cc = i & (CT - 1);
        xs[i]           = xb[pq * Cc + cc];
        xs[Ns * CT + i] = xb[Ns * Cc + pq * Cc + cc];
        rs[i]           = Rb[pq * Cc + cc];
    }
    __syncthreads();

    const int c = t & (CT - 1);
    const int r = t >> 5;               // 0..13
    const int bsel = (r >= 7) ? 1 : 0;
    const int m = r - 7 * bsel;         // 0..6 -> rows m, m+7
    const float* xsb = xs + bsel * Ns * CT;

    v2f acc[14];
    #pragma unroll
    for (int n = 0; n < 14; ++n) acc[n] = 0.0f;

    #pragma unroll 1
    for (int p = 0; p < 14; ++p) {
        int dm1 = m - p; if (dm1 < 0) dm1 += 14;
        int dm2 = dm1 + 7; if (dm2 >= 14) dm2 -= 14;
        v2f Rr[14];
        #pragma unroll
        for (int dn = 0; dn < 14; ++dn) {
            Rr[dn].x = rs[(dm1 * 14 + dn) * CT + c];
            Rr[dn].y = rs[(dm2 * 14 + dn) * CT + c];
        }
        #pragma unroll
        for (int q = 0; q < 14; ++q) {
            float xv = xsb[(p * 14 + q) * CT + c];
            v2f xv2 = {xv, xv};
            #pragma unroll
            for (int n = 0; n < 14; ++n) {
                acc[n] += xv2 * Rr[(n - q + 14) % 14];   // compile-time index
            }
        }
    }

    const int b = b0 + bsel;
    float* o1 = out + ((size_t)b * Ns + m * 14) * Cc + c0 + c;
    float* o2 = o1 + (size_t)(7 * 14) * Cc;
    #pragma unroll
    for (int n = 0; n < 14; ++n) {
        o1[n * Cc] = acc[n].x;
        o2[n * Cc] = acc[n].y;
    }
}

extern "C" void kernel_launch(void* const* d_in, const int* in_sizes, int n_in,
                              void* d_out, int out_size, void* d_ws, size_t ws_size,
                              hipStream_t stream) {
    const float* x  = (const float*)d_in[0];
    const float* cw = (const float*)d_in[1];
    float* outp = (float*)d_out;
    float* R = (float*)d_ws;                    // 196*512 floats
    float* T = R + (size_t)Ns * Cc;             // 14*14*512*2 floats

    prep_a_kernel<<<392, 256, 0, stream>>>(cw, T);
    prep_b_kernel<<<392, 256, 0, stream>>>(T, R);
    conv_kernel<<<128 * 16, CONV_THREADS, 0, stream>>>(x, R, outp);
}